// Round 7
// baseline (211.240 us; speedup 1.0000x reference)
//
#include <hip/hip_runtime.h>

#define E_EDGES 1000000
#define EBLK (E_EDGES / 64)      // 15625
#define NNODES 100000
#define NGBLK ((NNODES + 63) / 64) // 1563 (1563*64 = 100032 = padded row count)
#define LATENT 128
#define DIN 288
#define H1DIM 128
#define PAD1 136                 // halfs; 272 B stride, 16B-mult
#define PAD2 66                  // halfs; scalar b16 access only
#define PADA 296                 // mono fallback tile stride
#define PADQ 144                 // BYTES: int8 staging tile stride (16B-mult)

// ---- split-path ws layout (bf16-element offsets) ----
#define WT1A 0                   // [128][128] n-major bf16: wt1a[n][k]=W1[k][n]
#define WT1B 16384               // [128][128] bf16: wt1b[n][k]=W1[128+k][n]
#define WT2S 32768               // [64][128] bf16:  wt2[f][k]=W2[k][f]
#define TPOFF 40960              // f32[13][128] (occupies 3328 bf16 slots)
#define USCALE_E 44288           // f32[100032][4] group scales for U (16B/row)
#define VSCALE_E 844544          // f32[100032][4] group scales for V
#define UQ_E 1644800             // uint8[100032][128] (byte off 3289600, 16B-mult)
#define VQ_E 8046848             // uint8[100032][128]
#define WS_SPLIT ((size_t)14448896 * 2)   // ~28.9 MB

// ---- mono fallback layout ----
#define MW1 0                    // [128][288]
#define MW2 36864                // [64][128]

typedef __bf16 v8bf __attribute__((ext_vector_type(8)));
typedef __bf16 v4bf __attribute__((ext_vector_type(4)));
typedef __bf16 v2bf __attribute__((ext_vector_type(2)));
typedef float  v4f  __attribute__((ext_vector_type(4)));

__device__ __forceinline__ void cvt_store4(__bf16* p, float4 v) {
    v4bf o;
    o[0] = (__bf16)v.x; o[1] = (__bf16)v.y; o[2] = (__bf16)v.z; o[3] = (__bf16)v.w;
    *(v4bf*)p = o;
}

// dequant+combine 16 elems from biased-uint8: dst = relu(su*uq + sv*vq + t + c)
// where c = -128*(su+sv) folds the bias out; (x>>k)&0xff -> v_cvt_f32_ubyteK.
__device__ __forceinline__ void dequant16(__bf16* dst, int4 uw4, int4 vw4,
                                          const float4* tp, float su, float sv, float c) {
    int uw[4] = {uw4.x, uw4.y, uw4.z, uw4.w};
    int vw[4] = {vw4.x, vw4.y, vw4.z, vw4.w};
    #pragma unroll
    for (int h = 0; h < 2; ++h) {          // 8 elems per v8bf store
        float4 t0 = tp[2 * h], t1 = tp[2 * h + 1];
        int u0 = uw[2 * h], u1 = uw[2 * h + 1];
        int v0 = vw[2 * h], v1 = vw[2 * h + 1];
        v8bf o;
        o[0] = (__bf16)fmaxf(fmaf(su, (float)(unsigned)(u0 & 0xff),         fmaf(sv, (float)(unsigned)(v0 & 0xff),         t0.x + c)), 0.f);
        o[1] = (__bf16)fmaxf(fmaf(su, (float)(unsigned)((u0 >> 8) & 0xff),  fmaf(sv, (float)(unsigned)((v0 >> 8) & 0xff),  t0.y + c)), 0.f);
        o[2] = (__bf16)fmaxf(fmaf(su, (float)(unsigned)((u0 >> 16) & 0xff), fmaf(sv, (float)(unsigned)((v0 >> 16) & 0xff), t0.z + c)), 0.f);
        o[3] = (__bf16)fmaxf(fmaf(su, (float)(unsigned)((u0 >> 24) & 0xff), fmaf(sv, (float)(unsigned)((v0 >> 24) & 0xff), t0.w + c)), 0.f);
        o[4] = (__bf16)fmaxf(fmaf(su, (float)(unsigned)(u1 & 0xff),         fmaf(sv, (float)(unsigned)(v1 & 0xff),         t1.x + c)), 0.f);
        o[5] = (__bf16)fmaxf(fmaf(su, (float)(unsigned)((u1 >> 8) & 0xff),  fmaf(sv, (float)(unsigned)((v1 >> 8) & 0xff),  t1.y + c)), 0.f);
        o[6] = (__bf16)fmaxf(fmaf(su, (float)(unsigned)((u1 >> 16) & 0xff), fmaf(sv, (float)(unsigned)((v1 >> 16) & 0xff), t1.z + c)), 0.f);
        o[7] = (__bf16)fmaxf(fmaf(su, (float)(unsigned)((u1 >> 24) & 0xff), fmaf(sv, (float)(unsigned)((v1 >> 24) & 0xff), t1.w + c)), 0.f);
        *(v8bf*)(dst + 8 * h) = o;
    }
}

// ===================== split path =====================

// weights transpose + T' table (T'[b][n] = b1[n] + sum_k emb[b][k]*W1[256+k][n])
__global__ void prep_split(const float* __restrict__ W1, const float* __restrict__ W2,
                           const float* __restrict__ embed, const float* __restrict__ b1,
                           __bf16* __restrict__ ws) {
    int i = blockIdx.x * 256 + threadIdx.x;
    if (i < 16384) {                       // wt1a
        int n = i >> 7, k = i & 127;
        ws[WT1A + i] = (__bf16)W1[k * 128 + n];
    } else if (i < 32768) {                // wt1b
        int idx = i - 16384;
        int n = idx >> 7, k = idx & 127;
        ws[WT1B + idx] = (__bf16)W1[(128 + k) * 128 + n];
    } else if (i < 40960) {                // wt2
        int idx = i - 32768;
        int f = idx >> 7, k = idx & 127;
        ws[WT2S + idx] = (__bf16)W2[k * 64 + f];
    } else if (i < 40960 + 1664) {         // T' (f32)
        int idx = i - 40960;
        int b = idx >> 7, n = idx & 127;
        float s = b1[n];
        #pragma unroll
        for (int k = 0; k < 32; ++k)
            s += embed[b * 32 + k] * W1[(256 + k) * 128 + n];
        ((float*)(ws + TPOFF))[idx] = s;
    }
}

// node-major GEMM: U = z @ W1a, V = z @ W1b  (64 nodes/block, K=128)
// Per-32-feat-GROUP scales: wave w computes exactly feats [32w,32w+32), so the
// col16 butterfly directly yields the group max -> no cross-wave LDS reduction,
// barriers 9 -> 5. Quantized as biased uint8 (q+128). Accuracy >= per-row scale.
__global__ __launch_bounds__(256, 4) void node_gemm(
    const float* __restrict__ z, const __bf16* __restrict__ ws, __bf16* __restrict__ wsm)
{
    __shared__ __align__(16) __bf16 sA[64 * PAD1];
    __shared__ __align__(16) char  sQ[64 * PADQ];   // uint8 staging tile
    __shared__ __align__(16) float sSc[64 * 4];      // [row][group] scales
    const int tid = threadIdx.x;
    const int n0 = blockIdx.x * 64;

    // stage 64 node rows (coalesced, f32 -> bf16); quarter-wave = 4 rows x 64B
    {
        const int r = tid >> 2, j = tid & 3;
        int nd = n0 + r; if (nd >= NNODES) nd = NNODES - 1;   // clamp (dup rows OK)
        const float4* zs = (const float4*)(z + (size_t)nd * LATENT);
        __bf16* rowp = &sA[r * PAD1];
        #pragma unroll
        for (int i = 0; i < 8; ++i) { int p = j + 4 * i; cvt_store4(rowp + p * 4, zs[p]); }
    }
    __syncthreads();

    const int wave = tid >> 6, lane = tid & 63, quad = lane >> 4, col16 = lane & 15;
    v4f zero4 = {0.f, 0.f, 0.f, 0.f};

    #pragma unroll
    for (int pass = 0; pass < 2; ++pass) {
        const __bf16* wt = ws + (pass == 0 ? WT1A : WT1B);
        unsigned char* qout = (unsigned char*)(wsm + (pass == 0 ? UQ_E : VQ_E)) + (size_t)n0 * 128;
        float* scOut = (float*)(wsm + (pass == 0 ? USCALE_E : VSCALE_E)) + (size_t)n0 * 4;
        const __bf16* w1p0 = wt + (size_t)(wave * 32 + 2 * col16) * 128;
        const __bf16* w1p1 = w1p0 + 128;
        v4f acc[4][2];
        #pragma unroll
        for (int mt = 0; mt < 4; ++mt) { acc[mt][0] = zero4; acc[mt][1] = zero4; }
        #pragma unroll
        for (int ks = 0; ks < 4; ++ks) {
            int k0 = ks * 32 + quad * 8;
            v8bf a0 = *(const v8bf*)&sA[(0 * 16 + col16) * PAD1 + k0];
            v8bf a1 = *(const v8bf*)&sA[(1 * 16 + col16) * PAD1 + k0];
            v8bf a2 = *(const v8bf*)&sA[(2 * 16 + col16) * PAD1 + k0];
            v8bf a3 = *(const v8bf*)&sA[(3 * 16 + col16) * PAD1 + k0];
            v8bf bb0 = *(const v8bf*)&w1p0[k0];
            v8bf bb1 = *(const v8bf*)&w1p1[k0];
            acc[0][0] = __builtin_amdgcn_mfma_f32_16x16x32_bf16(a0, bb0, acc[0][0], 0, 0, 0);
            acc[1][0] = __builtin_amdgcn_mfma_f32_16x16x32_bf16(a1, bb0, acc[1][0], 0, 0, 0);
            acc[2][0] = __builtin_amdgcn_mfma_f32_16x16x32_bf16(a2, bb0, acc[2][0], 0, 0, 0);
            acc[3][0] = __builtin_amdgcn_mfma_f32_16x16x32_bf16(a3, bb0, acc[3][0], 0, 0, 0);
            acc[0][1] = __builtin_amdgcn_mfma_f32_16x16x32_bf16(a0, bb1, acc[0][1], 0, 0, 0);
            acc[1][1] = __builtin_amdgcn_mfma_f32_16x16x32_bf16(a1, bb1, acc[1][1], 0, 0, 0);
            acc[2][1] = __builtin_amdgcn_mfma_f32_16x16x32_bf16(a2, bb1, acc[2][1], 0, 0, 0);
            acc[3][1] = __builtin_amdgcn_mfma_f32_16x16x32_bf16(a3, bb1, acc[3][1], 0, 0, 0);
        }

        // ---- per-(row, group) |max|: lane partial over its 2 cols, col16 butterfly ----
        float rmx[4][4];
        #pragma unroll
        for (int mt = 0; mt < 4; ++mt)
            #pragma unroll
            for (int rr = 0; rr < 4; ++rr)
                rmx[mt][rr] = fmaxf(fabsf(acc[mt][0][rr]), fabsf(acc[mt][1][rr]));
        #pragma unroll
        for (int d = 1; d < 16; d <<= 1)
            #pragma unroll
            for (int mt = 0; mt < 4; ++mt)
                #pragma unroll
                for (int rr = 0; rr < 4; ++rr)
                    rmx[mt][rr] = fmaxf(rmx[mt][rr], __shfl_xor(rmx[mt][rr], d));
        // group max in every lane now; wave == group index.

        // ---- quantize into sQ (biased uint8) + stage scales ----
        #pragma unroll
        for (int mt = 0; mt < 4; ++mt) {
            #pragma unroll
            for (int rr = 0; rr < 4; ++rr) {
                int m = mt * 16 + quad * 4 + rr;
                float mx = rmx[mt][rr];
                float si = (mx > 0.f) ? (127.f / mx) : 0.f;
                int q0 = (int)rintf(acc[mt][0][rr] * si) + 128;
                int q1 = (int)rintf(acc[mt][1][rr] * si) + 128;
                *(unsigned short*)&sQ[m * PADQ + wave * 32 + 2 * col16] =
                    (unsigned short)((q0 & 255) | ((q1 & 255) << 8));
                if (col16 == 0)
                    sSc[m * 4 + wave] = mx * (1.f / 127.f);
            }
        }
        __syncthreads();                 // sQ + sSc ready

        // ---- coalesced stores: 8 KB tile + 1 KB scales ----
        {
            #pragma unroll
            for (int i = 0; i < 2; ++i) {
                int idx = tid * 16 + i * 4096;       // 0..8191 bytes of tile
                int m = idx >> 7, c = idx & 127;
                *(int4*)&qout[idx] = *(const int4*)&sQ[m * PADQ + c];
            }
            if (tid < 64)
                *(float4*)&scOut[tid * 4] = *(const float4*)&sSc[tid * 4];
        }
        __syncthreads();                 // reads done before next pass overwrites
    }
}

// edge kernel: gather uint8 U[src],V[dst] + group scales + T'[b] -> relu -> sH1
// -> GEMM2 -> GEMM3+softplus.
// Gather: thread j loads row bytes [16j,+16) and [64+16j,+16): each quad-instr
// covers ONE full 64B line (R6 layout, request-optimal). Scales: one float4
// (all 4 groups) per row, quad-broadcast. Dequant via v_cvt_f32_ubyteN with
// the +128 bias folded into the T' add.
__global__ __launch_bounds__(256, 8) void edge_kernel(
    const int* __restrict__ eidx, const int* __restrict__ bt,
    const float* __restrict__ b2, const float* __restrict__ W3,
    const float* __restrict__ b3, const __bf16* __restrict__ ws,
    float* __restrict__ out)
{
    __shared__ __align__(16) __bf16 sbuf[64 * PAD1];
    __shared__ float sb2[64];
    __shared__ float sw3[64];
    __shared__ float sb3s;
    __bf16* sH1 = sbuf;                 // [64][PAD1] phase 1
    __bf16* sH2 = sbuf;                 // [64][PAD2] phase 2 (aliased after barrier)

    const __bf16* wt2 = ws + WT2S;
    const float*  tpf = (const float*)(ws + TPOFF);
    const unsigned char* UQ = (const unsigned char*)(ws + UQ_E);
    const unsigned char* VQ = (const unsigned char*)(ws + VQ_E);
    const float* Usc = (const float*)(ws + USCALE_E);
    const float* Vsc = (const float*)(ws + VSCALE_E);

    const int tid = threadIdx.x;
    const int e0 = blockIdx.x * 64;

    if (tid < 64) sb2[tid] = b2[tid];
    else if (tid < 128) sw3[tid - 64] = W3[tid - 64];
    else if (tid == 128) sb3s = b3[0];

    // ---- gather + dequant + combine: thread owns elems [16j,+16) and [64+16j,+16) ----
    {
        const int r = tid >> 2, j = tid & 3;
        const int e = e0 + r;
        const int isrc = __builtin_nontemporal_load(eidx + e);
        const int idst = __builtin_nontemporal_load(eidx + E_EDGES + e);
        const int ib   = __builtin_nontemporal_load(bt + e);
        float4 su4 = *(const float4*)(Usc + (size_t)isrc * 4);
        float4 sv4 = *(const float4*)(Vsc + (size_t)idst * 4);
        const unsigned char* uqr = UQ + (size_t)isrc * 128;
        const unsigned char* vqr = VQ + (size_t)idst * 128;
        int4 uA = *(const int4*)(uqr + 16 * j);
        int4 uB = *(const int4*)(uqr + 64 + 16 * j);
        int4 vA = *(const int4*)(vqr + 16 * j);
        int4 vB = *(const int4*)(vqr + 64 + 16 * j);
        // group of first half = j>>1 in {0,1}; second half = 2+(j>>1) in {2,3}
        float sua = (j & 2) ? su4.y : su4.x;
        float sub = (j & 2) ? su4.w : su4.z;
        float sva = (j & 2) ? sv4.y : sv4.x;
        float svb = (j & 2) ? sv4.w : sv4.z;
        float c0 = -128.f * (sua + sva);
        float c1 = -128.f * (sub + svb);
        const float* tpr = tpf + ib * 128;
        __bf16* rowp = &sH1[r * PAD1];
        dequant16(rowp + 16 * j,      uA, vA, (const float4*)(tpr + 16 * j),      sua, sva, c0);
        dequant16(rowp + 64 + 16 * j, uB, vB, (const float4*)(tpr + 64 + 16 * j), sub, svb, c1);
    }
    __syncthreads();                    // B1: sH1 ready

    const int wave = tid >> 6, lane = tid & 63, quad = lane >> 4, col16 = lane & 15;
    v4f zero4 = {0.f, 0.f, 0.f, 0.f};

    // ---- GEMM2: wave owns feat wave*16+col16; A=sH1 LDS, B=wt2 global ----
    v4f acc2[4];
    #pragma unroll
    for (int mt = 0; mt < 4; ++mt) acc2[mt] = zero4;

    const __bf16* w2p = wt2 + (size_t)(wave * 16 + col16) * H1DIM;
    #pragma unroll
    for (int ks = 0; ks < 4; ++ks) {
        int k0 = ks * 32 + quad * 8;
        v8bf bb = *(const v8bf*)&w2p[k0];
        #pragma unroll
        for (int mt = 0; mt < 4; ++mt) {
            v8bf aa = *(const v8bf*)&sH1[(mt * 16 + col16) * PAD1 + k0];
            acc2[mt] = __builtin_amdgcn_mfma_f32_16x16x32_bf16(aa, bb, acc2[mt], 0, 0, 0);
        }
    }
    __syncthreads();                    // B2: sH1 reads done (sH2 aliases sH1)

    // ---- epi2: bias+relu -> sH2 edge-major ----
    {
        int n = wave * 16 + col16;
        float bias = sb2[n];
        #pragma unroll
        for (int mt = 0; mt < 4; ++mt) {
            #pragma unroll
            for (int rr = 0; rr < 4; ++rr) {
                int m = mt * 16 + quad * 4 + rr;
                sH2[m * PAD2 + n] = (__bf16)fmaxf(acc2[mt][rr] + bias, 0.f);
            }
        }
    }
    __syncthreads();                    // B3: sH2 ready

    // ---- GEMM3 + softplus ----
    {
        int row = tid >> 2;
        int q   = tid & 3;
        float s = 0.f;
        #pragma unroll
        for (int kk = 0; kk < 16; ++kk) {
            int k = q * 16 + kk;
            s += (float)sH2[row * PAD2 + k] * sw3[k];
        }
        s += __shfl_xor(s, 1);
        s += __shfl_xor(s, 2);
        if (q == 0) {
            float x = s + sb3s;
            float r = fmaxf(x, 0.f) + log1pf(expf(-fabsf(x)));
            __builtin_nontemporal_store(r, out + e0 + row);
        }
    }
}

// ===================== mono fallback =====================

__global__ void prep_mono(const float* __restrict__ W1, const float* __restrict__ W2,
                          __bf16* __restrict__ ws) {
    int i = blockIdx.x * 256 + threadIdx.x;
    if (i < DIN * H1DIM) {
        int n = i / DIN, k = i - n * DIN;
        ws[MW1 + i] = (__bf16)W1[k * H1DIM + n];
    }
    if (i < H1DIM * 64) {
        int n = i / H1DIM, k = i - n * H1DIM;
        ws[MW2 + i] = (__bf16)W2[k * 64 + n];
    }
}

__global__ __launch_bounds__(256, 4) void fused_mono(
    const float* __restrict__ z, const int* __restrict__ eidx,
    const int* __restrict__ bt, const float* __restrict__ embed,
    const float* __restrict__ b1, const float* __restrict__ b2,
    const float* __restrict__ W3, const float* __restrict__ b3,
    const __bf16* __restrict__ ws, float* __restrict__ out)
{
    __shared__ __align__(16) __bf16 sbuf[64 * PADA];
    __shared__ __bf16 sH2[64 * PAD2];
    __shared__ float sb1[H1DIM];
    __shared__ float sb2[64];
    __shared__ float sw3[64];
    __shared__ float sb3s;
    __bf16* sA  = sbuf;
    __bf16* sH1 = sbuf;

    const __bf16* wt1 = ws + MW1;
    const __bf16* wt2 = ws + MW2;
    const int tid = threadIdx.x;
    const int e0 = blockIdx.x * 64;

    if (tid < 128) sb1[tid] = b1[tid];
    else if (tid < 192) sb2[tid - 128] = b2[tid - 128];
    else { int k = tid - 192; sw3[k] = W3[k]; if (k == 0) sb3s = b3[0]; }

    {
        const int r = tid >> 2, j = tid & 3;
        const int e = e0 + r;
        const int isrc = eidx[e];
        const int idst = eidx[E_EDGES + e];
        const int ib   = bt[e];
        const float4* zs = (const float4*)(z + (size_t)isrc * LATENT);
        const float4* zd = (const float4*)(z + (size_t)idst * LATENT);
        const float4* em = (const float4*)(embed + (size_t)ib * 32);
        __bf16* rowp = &sA[r * PADA];
        #pragma unroll
        for (int i = 0; i < 8; ++i) { int p = j + 4 * i; cvt_store4(rowp + p * 4, zs[p]); }
        #pragma unroll
        for (int i = 0; i < 8; ++i) { int p = j + 4 * i; cvt_store4(rowp + 128 + p * 4, zd[p]); }
        #pragma unroll
        for (int i = 0; i < 2; ++i) { int p = j + 4 * i; cvt_store4(rowp + 256 + p * 4, em[p]); }
    }
    __syncthreads();

    const int wave = tid >> 6, lane = tid & 63, quad = lane >> 4, col16 = lane & 15;
    v4f zero4 = {0.f, 0.f, 0.f, 0.f};
    v4f acc[4][2];
    #pragma unroll
    for (int mt = 0; mt < 4; ++mt) { acc[mt][0] = zero4; acc[mt][1] = zero4; }

    const __bf16* w1p0 = wt1 + (size_t)(wave * 32 + col16) * DIN;
    const __bf16* w1p1 = wt1 + (size_t)(wave * 32 + 16 + col16) * DIN;

    #pragma unroll
    for (int ks = 0; ks < 9; ++ks) {
        int k0 = ks * 32 + quad * 8;
        v8bf a0 = *(const v8bf*)&sA[(0 * 16 + col16) * PADA + k0];
        v8bf a1 = *(const v8bf*)&sA[(1 * 16 + col16) * PADA + k0];
        v8bf a2 = *(const v8bf*)&sA[(2 * 16 + col16) * PADA + k0];
        v8bf a3 = *(const v8bf*)&sA[(3 * 16 + col16) * PADA + k0];
        v8bf bb0 = *(const v8bf*)&w1p0[k0];
        v8bf bb1 = *(const v8bf*)&w1p1[k0];
        acc[0][0] = __builtin_amdgcn_mfma_f32_16x16x32_bf16(a0, bb0, acc[0][0], 0, 0, 0);
        acc[1][0] = __builtin_amdgcn_mfma_f32_16x16x32_bf16(a1, bb0, acc[1][0], 0, 0, 0);
        acc[2][0] = __builtin_amdgcn_mfma_f32_16x16x32_bf16(a2, bb0, acc[2][0], 0, 0, 0);
        acc[3][0] = __builtin_amdgcn_mfma_f32_16x16x32_bf16(a3, bb0, acc[3][0], 0, 0, 0);
        acc[0][1] = __builtin_amdgcn_mfma_f32_16x16x32_bf16(a0, bb1, acc[0][1], 0, 0, 0);
        acc[1][1] = __builtin_amdgcn_mfma_f32_16x16x32_bf16(a1, bb1, acc[1][1], 0, 0, 0);
        acc[2][1] = __builtin_amdgcn_mfma_f32_16x16x32_bf16(a2, bb1, acc[2][1], 0, 0, 0);
        acc[3][1] = __builtin_amdgcn_mfma_f32_16x16x32_bf16(a3, bb1, acc[3][1], 0, 0, 0);
    }
    __syncthreads();

    #pragma unroll
    for (int j = 0; j < 2; ++j) {
        int n = wave * 32 + j * 16 + col16;
        float bias = sb1[n];
        #pragma unroll
        for (int mt = 0; mt < 4; ++mt) {
            #pragma unroll
            for (int r = 0; r < 4; ++r) {
                int m = mt * 16 + quad * 4 + r;
                sH1[m * PAD1 + n] = (__bf16)fmaxf(acc[mt][j][r] + bias, 0.f);
            }
        }
    }
    __syncthreads();

    v4f acc2[4];
    #pragma unroll
    for (int mt = 0; mt < 4; ++mt) acc2[mt] = zero4;
    const __bf16* w2p = wt2 + (size_t)(wave * 16 + col16) * H1DIM;
    #pragma unroll
    for (int ks = 0; ks < 4; ++ks) {
        int k0 = ks * 32 + quad * 8;
        v8bf bb = *(const v8bf*)&w2p[k0];
        #pragma unroll
        for (int mt = 0; mt < 4; ++mt) {
            v8bf aa = *(const v8bf*)&sH1[(mt * 16 + col16) * PAD1 + k0];
            acc2[mt] = __builtin_amdgcn_mfma_f32_16x16x32_bf16(aa, bb, acc2[mt], 0, 0, 0);
        }
    }
    {
        int n = wave * 16 + col16;
        float bias = sb2[n];
        #pragma unroll
        for (int mt = 0; mt < 4; ++mt) {
            #pragma unroll
            for (int rr = 0; rr < 4; ++rr) {
                int m = mt * 16 + quad * 4 + rr;
                sH2[m * PAD2 + n] = (__bf16)fmaxf(acc2[mt][rr] + bias, 0.f);
            }
        }
    }
    __syncthreads();
    {
        int row = tid >> 2, q = tid & 3;
        float s = 0.f;
        #pragma unroll
        for (int kk = 0; kk < 16; ++kk) {
            int k = q * 16 + kk;
            s += (float)sH2[row * PAD2 + k] * sw3[k];
        }
        s += __shfl_xor(s, 1);
        s += __shfl_xor(s, 2);
        if (q == 0) {
            float x = s + sb3s;
            out[e0 + row] = fmaxf(x, 0.f) + log1pf(expf(-fabsf(x)));
        }
    }
}

extern "C" void kernel_launch(void* const* d_in, const int* in_sizes, int n_in,
                              void* d_out, int out_size, void* d_ws, size_t ws_size,
                              hipStream_t stream) {
    const float* z     = (const float*)d_in[0];
    const int*   eidx  = (const int*)d_in[1];
    const int*   btyp  = (const int*)d_in[2];
    const float* embed = (const float*)d_in[3];
    const float* W1    = (const float*)d_in[4];
    const float* b1    = (const float*)d_in[5];
    const float* W2    = (const float*)d_in[6];
    const float* b2    = (const float*)d_in[7];
    const float* W3    = (const float*)d_in[8];
    const float* b3    = (const float*)d_in[9];
    float* out = (float*)d_out;
    __bf16* ws = (__bf16*)d_ws;

    if (ws_size >= WS_SPLIT) {
        prep_split<<<167, 256, 0, stream>>>(W1, W2, embed, b1, ws);
        node_gemm<<<NGBLK, 256, 0, stream>>>(z, ws, ws);
        edge_kernel<<<EBLK, 256, 0, stream>>>(eidx, btyp, b2, W3, b3, ws, out);
    } else {
        prep_mono<<<(DIN * H1DIM + 255) / 256, 256, 0, stream>>>(W1, W2, ws);
        fused_mono<<<EBLK, 256, 0, stream>>>(z, eidx, btyp, embed,
                                             b1, b2, W3, b3, ws, out);
    }
}

// Round 8
// 199.185 us; speedup vs baseline: 1.0605x; 1.0605x over previous
//
#include <hip/hip_runtime.h>

#define E_EDGES 1000000
#define EBLK (E_EDGES / 64)      // 15625
#define NNODES 100000
#define NGBLK ((NNODES + 63) / 64) // 1563 (1563*64 = 100032 = padded row count)
#define LATENT 128
#define DIN 288
#define H1DIM 128
#define PAD1 136                 // halfs; 272 B stride, 16B-mult
#define PAD2 66                  // halfs; scalar b16 access only
#define PADA 296                 // mono fallback tile stride
#define PADQ 144                 // BYTES: int8 staging tile stride (16B-mult)

// ---- split-path ws layout (bf16-element offsets) ----
#define WT1A 0                   // [128][128] n-major bf16: wt1a[n][k]=W1[k][n]
#define WT1B 16384               // [128][128] bf16: wt1b[n][k]=W1[128+k][n]
#define WT2S 32768               // [64][128] bf16:  wt2[f][k]=W2[k][f]
#define TPOFF 40960              // f32[13][128] (occupies 3328 bf16 slots)
#define USCALE_E 44288           // f32[100032] row scales for U
#define VSCALE_E 244352          // f32[100032] row scales for V
#define UQ_E 444416              // int8[100032][128] (byte off 888832, 16B-mult)
#define VQ_E 6846464             // int8[100032][128]
#define WS_SPLIT ((size_t)13248512 * 2)   // ~26.5 MB

// ---- mono fallback layout ----
#define MW1 0                    // [128][288]
#define MW2 36864                // [64][128]

typedef __bf16 v8bf __attribute__((ext_vector_type(8)));
typedef __bf16 v4bf __attribute__((ext_vector_type(4)));
typedef __bf16 v2bf __attribute__((ext_vector_type(2)));
typedef float  v4f  __attribute__((ext_vector_type(4)));

__device__ __forceinline__ void cvt_store4(__bf16* p, float4 v) {
    v4bf o;
    o[0] = (__bf16)v.x; o[1] = (__bf16)v.y; o[2] = (__bf16)v.z; o[3] = (__bf16)v.w;
    *(v4bf*)p = o;
}

// dequant+combine 16 elems: dst[0..15] = relu(su*u + sv*v + t)
__device__ __forceinline__ void dequant16(__bf16* dst, int4 uw4, int4 vw4,
                                          const float4* tp, float su, float sv) {
    int uw[4] = {uw4.x, uw4.y, uw4.z, uw4.w};
    int vw[4] = {vw4.x, vw4.y, vw4.z, vw4.w};
    #pragma unroll
    for (int h = 0; h < 2; ++h) {          // 8 elems per v8bf store
        float4 t0 = tp[2 * h], t1 = tp[2 * h + 1];
        int u0 = uw[2 * h], u1 = uw[2 * h + 1];
        int v0 = vw[2 * h], v1 = vw[2 * h + 1];
        v8bf o;
        o[0] = (__bf16)fmaxf(fmaf(su, (float)(signed char)(u0),       fmaf(sv, (float)(signed char)(v0),       t0.x)), 0.f);
        o[1] = (__bf16)fmaxf(fmaf(su, (float)(signed char)(u0 >> 8),  fmaf(sv, (float)(signed char)(v0 >> 8),  t0.y)), 0.f);
        o[2] = (__bf16)fmaxf(fmaf(su, (float)(signed char)(u0 >> 16), fmaf(sv, (float)(signed char)(v0 >> 16), t0.z)), 0.f);
        o[3] = (__bf16)fmaxf(fmaf(su, (float)(signed char)(u0 >> 24), fmaf(sv, (float)(signed char)(v0 >> 24), t0.w)), 0.f);
        o[4] = (__bf16)fmaxf(fmaf(su, (float)(signed char)(u1),       fmaf(sv, (float)(signed char)(v1),       t1.x)), 0.f);
        o[5] = (__bf16)fmaxf(fmaf(su, (float)(signed char)(u1 >> 8),  fmaf(sv, (float)(signed char)(v1 >> 8),  t1.y)), 0.f);
        o[6] = (__bf16)fmaxf(fmaf(su, (float)(signed char)(u1 >> 16), fmaf(sv, (float)(signed char)(v1 >> 16), t1.z)), 0.f);
        o[7] = (__bf16)fmaxf(fmaf(su, (float)(signed char)(u1 >> 24), fmaf(sv, (float)(signed char)(v1 >> 24), t1.w)), 0.f);
        *(v8bf*)(dst + 8 * h) = o;
    }
}

// ===================== split path =====================

// weights transpose + T' table (T'[b][n] = b1[n] + sum_k emb[b][k]*W1[256+k][n])
__global__ void prep_split(const float* __restrict__ W1, const float* __restrict__ W2,
                           const float* __restrict__ embed, const float* __restrict__ b1,
                           __bf16* __restrict__ ws) {
    int i = blockIdx.x * 256 + threadIdx.x;
    if (i < 16384) {                       // wt1a
        int n = i >> 7, k = i & 127;
        ws[WT1A + i] = (__bf16)W1[k * 128 + n];
    } else if (i < 32768) {                // wt1b
        int idx = i - 16384;
        int n = idx >> 7, k = idx & 127;
        ws[WT1B + idx] = (__bf16)W1[(128 + k) * 128 + n];
    } else if (i < 40960) {                // wt2
        int idx = i - 32768;
        int f = idx >> 7, k = idx & 127;
        ws[WT2S + idx] = (__bf16)W2[k * 64 + f];
    } else if (i < 40960 + 1664) {         // T' (f32)
        int idx = i - 40960;
        int b = idx >> 7, n = idx & 127;
        float s = b1[n];
        #pragma unroll
        for (int k = 0; k < 32; ++k)
            s += embed[b * 32 + k] * W1[(256 + k) * 128 + n];
        ((float*)(ws + TPOFF))[idx] = s;
    }
}

// node-major GEMM: U = z @ W1a, V = z @ W1b  (64 nodes/block, K=128)
// Epilogue quantizes each output row to int8 with per-row scale s = rowmax/127.
// R5/R6 measured: absmax unchanged (0.0156) -> int8 row-scale is accuracy-free.
// R7 lesson: per-GROUP scales (4x table, 16B/row gather) cost +60MB FETCH in
// edge; per-ROW 4B scales keep the table 0.8MB and L2-hot. Keep per-row.
__global__ __launch_bounds__(256, 4) void node_gemm(
    const float* __restrict__ z, const __bf16* __restrict__ ws, __bf16* __restrict__ wsm)
{
    __shared__ __align__(16) __bf16 sA[64 * PAD1];
    __shared__ __align__(16) char  sQ[64 * PADQ];   // int8 staging tile
    __shared__ float smx[256];                       // [wave][row] partial maxes
    __shared__ float sinvS[64];                      // 127/rowmax
    const int tid = threadIdx.x;
    const int n0 = blockIdx.x * 64;

    // stage 64 node rows (coalesced, f32 -> bf16); quarter-wave = 4 rows x 64B
    {
        const int r = tid >> 2, j = tid & 3;
        int nd = n0 + r; if (nd >= NNODES) nd = NNODES - 1;   // clamp (dup rows OK)
        const float4* zs = (const float4*)(z + (size_t)nd * LATENT);
        __bf16* rowp = &sA[r * PAD1];
        #pragma unroll
        for (int i = 0; i < 8; ++i) { int p = j + 4 * i; cvt_store4(rowp + p * 4, zs[p]); }
    }
    __syncthreads();

    const int wave = tid >> 6, lane = tid & 63, quad = lane >> 4, col16 = lane & 15;
    v4f zero4 = {0.f, 0.f, 0.f, 0.f};

    #pragma unroll
    for (int pass = 0; pass < 2; ++pass) {
        const __bf16* wt = ws + (pass == 0 ? WT1A : WT1B);
        signed char* qout = (signed char*)(wsm + (pass == 0 ? UQ_E : VQ_E)) + (size_t)n0 * 128;
        float* scOut = (float*)(wsm + (pass == 0 ? USCALE_E : VSCALE_E)) + n0;
        const __bf16* w1p0 = wt + (size_t)(wave * 32 + 2 * col16) * 128;
        const __bf16* w1p1 = w1p0 + 128;
        v4f acc[4][2];
        #pragma unroll
        for (int mt = 0; mt < 4; ++mt) { acc[mt][0] = zero4; acc[mt][1] = zero4; }
        #pragma unroll
        for (int ks = 0; ks < 4; ++ks) {
            int k0 = ks * 32 + quad * 8;
            v8bf a0 = *(const v8bf*)&sA[(0 * 16 + col16) * PAD1 + k0];
            v8bf a1 = *(const v8bf*)&sA[(1 * 16 + col16) * PAD1 + k0];
            v8bf a2 = *(const v8bf*)&sA[(2 * 16 + col16) * PAD1 + k0];
            v8bf a3 = *(const v8bf*)&sA[(3 * 16 + col16) * PAD1 + k0];
            v8bf bb0 = *(const v8bf*)&w1p0[k0];
            v8bf bb1 = *(const v8bf*)&w1p1[k0];
            acc[0][0] = __builtin_amdgcn_mfma_f32_16x16x32_bf16(a0, bb0, acc[0][0], 0, 0, 0);
            acc[1][0] = __builtin_amdgcn_mfma_f32_16x16x32_bf16(a1, bb0, acc[1][0], 0, 0, 0);
            acc[2][0] = __builtin_amdgcn_mfma_f32_16x16x32_bf16(a2, bb0, acc[2][0], 0, 0, 0);
            acc[3][0] = __builtin_amdgcn_mfma_f32_16x16x32_bf16(a3, bb0, acc[3][0], 0, 0, 0);
            acc[0][1] = __builtin_amdgcn_mfma_f32_16x16x32_bf16(a0, bb1, acc[0][1], 0, 0, 0);
            acc[1][1] = __builtin_amdgcn_mfma_f32_16x16x32_bf16(a1, bb1, acc[1][1], 0, 0, 0);
            acc[2][1] = __builtin_amdgcn_mfma_f32_16x16x32_bf16(a2, bb1, acc[2][1], 0, 0, 0);
            acc[3][1] = __builtin_amdgcn_mfma_f32_16x16x32_bf16(a3, bb1, acc[3][1], 0, 0, 0);
        }

        // ---- per-row |max|: lane partial over its 2 cols, then col16 butterfly ----
        float rmx[4][4];
        #pragma unroll
        for (int mt = 0; mt < 4; ++mt)
            #pragma unroll
            for (int rr = 0; rr < 4; ++rr)
                rmx[mt][rr] = fmaxf(fabsf(acc[mt][0][rr]), fabsf(acc[mt][1][rr]));
        #pragma unroll
        for (int d = 1; d < 16; d <<= 1)
            #pragma unroll
            for (int mt = 0; mt < 4; ++mt)
                #pragma unroll
                for (int rr = 0; rr < 4; ++rr)
                    rmx[mt][rr] = fmaxf(rmx[mt][rr], __shfl_xor(rmx[mt][rr], d));
        if (col16 == 0) {
            #pragma unroll
            for (int mt = 0; mt < 4; ++mt)
                #pragma unroll
                for (int rr = 0; rr < 4; ++rr)
                    smx[wave * 64 + mt * 16 + quad * 4 + rr] = rmx[mt][rr];
        }
        __syncthreads();                 // smx ready

        if (tid < 64) {
            float mx = fmaxf(fmaxf(smx[tid], smx[64 + tid]),
                             fmaxf(smx[128 + tid], smx[192 + tid]));
            float s = 0.f, si = 0.f;
            if (mx > 0.f) { s = mx * (1.f / 127.f); si = 127.f / mx; }
            sinvS[tid] = si;
            scOut[tid] = s;              // global scale write (coalesced 256B)
        }
        __syncthreads();                 // sinvS ready

        // ---- quantize into sQ [64][PADQ] ----
        #pragma unroll
        for (int mt = 0; mt < 4; ++mt) {
            #pragma unroll
            for (int rr = 0; rr < 4; ++rr) {
                int m = mt * 16 + quad * 4 + rr;
                float si = sinvS[m];
                int q0 = (int)rintf(acc[mt][0][rr] * si);
                int q1 = (int)rintf(acc[mt][1][rr] * si);
                *(unsigned short*)&sQ[m * PADQ + wave * 32 + 2 * col16] =
                    (unsigned short)((q0 & 255) | ((q1 & 255) << 8));
            }
        }
        __syncthreads();                 // sQ ready

        // ---- coalesced 8 KB store ----
        {
            #pragma unroll
            for (int i = 0; i < 2; ++i) {
                int idx = tid * 16 + i * 4096;       // 0..8191 bytes of tile
                int m = idx >> 7, c = idx & 127;
                *(int4*)&qout[idx] = *(const int4*)&sQ[m * PADQ + c];
            }
        }
        __syncthreads();                 // sQ / smx reads done before next pass
    }
}

// edge kernel: gather int8 U[src],V[dst] + scales + T'[b] -> relu -> sH1 ->
// GEMM2 -> GEMM3+softplus.
// Gather layout (R6, measured best 84.6us): thread j loads row+16j and
// row+64+16j, so each quad-instruction covers ONE full 64B line -> 64
// row-requests/wave. Requests are the currency on this path, not bytes.
// Per-row 4B scales keep the scale tables 0.8MB total = L2-hot (R7 lesson).
__global__ __launch_bounds__(256, 8) void edge_kernel(
    const int* __restrict__ eidx, const int* __restrict__ bt,
    const float* __restrict__ b2, const float* __restrict__ W3,
    const float* __restrict__ b3, const __bf16* __restrict__ ws,
    float* __restrict__ out)
{
    __shared__ __align__(16) __bf16 sbuf[64 * PAD1];
    __shared__ float sb2[64];
    __shared__ float sw3[64];
    __shared__ float sb3s;
    __bf16* sH1 = sbuf;                 // [64][PAD1] phase 1
    __bf16* sH2 = sbuf;                 // [64][PAD2] phase 2 (aliased after barrier)

    const __bf16* wt2 = ws + WT2S;
    const float*  tpf = (const float*)(ws + TPOFF);
    const signed char* UQ = (const signed char*)(ws + UQ_E);
    const signed char* VQ = (const signed char*)(ws + VQ_E);
    const float* Usc = (const float*)(ws + USCALE_E);
    const float* Vsc = (const float*)(ws + VSCALE_E);

    const int tid = threadIdx.x;
    const int e0 = blockIdx.x * 64;

    if (tid < 64) sb2[tid] = b2[tid];
    else if (tid < 128) sw3[tid - 64] = W3[tid - 64];
    else if (tid == 128) sb3s = b3[0];

    // ---- gather + dequant + combine: thread owns elems [16j,16j+16) and [64+16j,..) ----
    {
        const int r = tid >> 2, j = tid & 3;
        const int e = e0 + r;
        const int isrc = __builtin_nontemporal_load(eidx + e);
        const int idst = __builtin_nontemporal_load(eidx + E_EDGES + e);
        const int ib   = __builtin_nontemporal_load(bt + e);
        const float su = Usc[isrc];
        const float sv = Vsc[idst];
        const signed char* uqr = UQ + (size_t)isrc * 128;
        const signed char* vqr = VQ + (size_t)idst * 128;
        int4 uA = *(const int4*)(uqr + 16 * j);
        int4 uB = *(const int4*)(uqr + 64 + 16 * j);
        int4 vA = *(const int4*)(vqr + 16 * j);
        int4 vB = *(const int4*)(vqr + 64 + 16 * j);
        const float* tpr = tpf + ib * 128;
        __bf16* rowp = &sH1[r * PAD1];
        dequant16(rowp + 16 * j,      uA, vA, (const float4*)(tpr + 16 * j),      su, sv);
        dequant16(rowp + 64 + 16 * j, uB, vB, (const float4*)(tpr + 64 + 16 * j), su, sv);
    }
    __syncthreads();                    // B1: sH1 ready

    const int wave = tid >> 6, lane = tid & 63, quad = lane >> 4, col16 = lane & 15;
    v4f zero4 = {0.f, 0.f, 0.f, 0.f};

    // ---- GEMM2: wave owns feat wave*16+col16; A=sH1 LDS, B=wt2 global ----
    v4f acc2[4];
    #pragma unroll
    for (int mt = 0; mt < 4; ++mt) acc2[mt] = zero4;

    const __bf16* w2p = wt2 + (size_t)(wave * 16 + col16) * H1DIM;
    #pragma unroll
    for (int ks = 0; ks < 4; ++ks) {
        int k0 = ks * 32 + quad * 8;
        v8bf bb = *(const v8bf*)&w2p[k0];
        #pragma unroll
        for (int mt = 0; mt < 4; ++mt) {
            v8bf aa = *(const v8bf*)&sH1[(mt * 16 + col16) * PAD1 + k0];
            acc2[mt] = __builtin_amdgcn_mfma_f32_16x16x32_bf16(aa, bb, acc2[mt], 0, 0, 0);
        }
    }
    __syncthreads();                    // B2: sH1 reads done (sH2 aliases sH1)

    // ---- epi2: bias+relu -> sH2 edge-major ----
    {
        int n = wave * 16 + col16;
        float bias = sb2[n];
        #pragma unroll
        for (int mt = 0; mt < 4; ++mt) {
            #pragma unroll
            for (int rr = 0; rr < 4; ++rr) {
                int m = mt * 16 + quad * 4 + rr;
                sH2[m * PAD2 + n] = (__bf16)fmaxf(acc2[mt][rr] + bias, 0.f);
            }
        }
    }
    __syncthreads();                    // B3: sH2 ready

    // ---- GEMM3 + softplus ----
    {
        int row = tid >> 2;
        int q   = tid & 3;
        float s = 0.f;
        #pragma unroll
        for (int kk = 0; kk < 16; ++kk) {
            int k = q * 16 + kk;
            s += (float)sH2[row * PAD2 + k] * sw3[k];
        }
        s += __shfl_xor(s, 1);
        s += __shfl_xor(s, 2);
        if (q == 0) {
            float x = s + sb3s;
            float r = fmaxf(x, 0.f) + log1pf(expf(-fabsf(x)));
            __builtin_nontemporal_store(r, out + e0 + row);
        }
    }
}

// ===================== mono fallback =====================

__global__ void prep_mono(const float* __restrict__ W1, const float* __restrict__ W2,
                          __bf16* __restrict__ ws) {
    int i = blockIdx.x * 256 + threadIdx.x;
    if (i < DIN * H1DIM) {
        int n = i / DIN, k = i - n * DIN;
        ws[MW1 + i] = (__bf16)W1[k * H1DIM + n];
    }
    if (i < H1DIM * 64) {
        int n = i / H1DIM, k = i - n * H1DIM;
        ws[MW2 + i] = (__bf16)W2[k * 64 + n];
    }
}

__global__ __launch_bounds__(256, 4) void fused_mono(
    const float* __restrict__ z, const int* __restrict__ eidx,
    const int* __restrict__ bt, const float* __restrict__ embed,
    const float* __restrict__ b1, const float* __restrict__ b2,
    const float* __restrict__ W3, const float* __restrict__ b3,
    const __bf16* __restrict__ ws, float* __restrict__ out)
{
    __shared__ __align__(16) __bf16 sbuf[64 * PADA];
    __shared__ __bf16 sH2[64 * PAD2];
    __shared__ float sb1[H1DIM];
    __shared__ float sb2[64];
    __shared__ float sw3[64];
    __shared__ float sb3s;
    __bf16* sA  = sbuf;
    __bf16* sH1 = sbuf;

    const __bf16* wt1 = ws + MW1;
    const __bf16* wt2 = ws + MW2;
    const int tid = threadIdx.x;
    const int e0 = blockIdx.x * 64;

    if (tid < 128) sb1[tid] = b1[tid];
    else if (tid < 192) sb2[tid - 128] = b2[tid - 128];
    else { int k = tid - 192; sw3[k] = W3[k]; if (k == 0) sb3s = b3[0]; }

    {
        const int r = tid >> 2, j = tid & 3;
        const int e = e0 + r;
        const int isrc = eidx[e];
        const int idst = eidx[E_EDGES + e];
        const int ib   = bt[e];
        const float4* zs = (const float4*)(z + (size_t)isrc * LATENT);
        const float4* zd = (const float4*)(z + (size_t)idst * LATENT);
        const float4* em = (const float4*)(embed + (size_t)ib * 32);
        __bf16* rowp = &sA[r * PADA];
        #pragma unroll
        for (int i = 0; i < 8; ++i) { int p = j + 4 * i; cvt_store4(rowp + p * 4, zs[p]); }
        #pragma unroll
        for (int i = 0; i < 8; ++i) { int p = j + 4 * i; cvt_store4(rowp + 128 + p * 4, zd[p]); }
        #pragma unroll
        for (int i = 0; i < 2; ++i) { int p = j + 4 * i; cvt_store4(rowp + 256 + p * 4, em[p]); }
    }
    __syncthreads();

    const int wave = tid >> 6, lane = tid & 63, quad = lane >> 4, col16 = lane & 15;
    v4f zero4 = {0.f, 0.f, 0.f, 0.f};
    v4f acc[4][2];
    #pragma unroll
    for (int mt = 0; mt < 4; ++mt) { acc[mt][0] = zero4; acc[mt][1] = zero4; }

    const __bf16* w1p0 = wt1 + (size_t)(wave * 32 + col16) * DIN;
    const __bf16* w1p1 = wt1 + (size_t)(wave * 32 + 16 + col16) * DIN;

    #pragma unroll
    for (int ks = 0; ks < 9; ++ks) {
        int k0 = ks * 32 + quad * 8;
        v8bf a0 = *(const v8bf*)&sA[(0 * 16 + col16) * PADA + k0];
        v8bf a1 = *(const v8bf*)&sA[(1 * 16 + col16) * PADA + k0];
        v8bf a2 = *(const v8bf*)&sA[(2 * 16 + col16) * PADA + k0];
        v8bf a3 = *(const v8bf*)&sA[(3 * 16 + col16) * PADA + k0];
        v8bf bb0 = *(const v8bf*)&w1p0[k0];
        v8bf bb1 = *(const v8bf*)&w1p1[k0];
        acc[0][0] = __builtin_amdgcn_mfma_f32_16x16x32_bf16(a0, bb0, acc[0][0], 0, 0, 0);
        acc[1][0] = __builtin_amdgcn_mfma_f32_16x16x32_bf16(a1, bb0, acc[1][0], 0, 0, 0);
        acc[2][0] = __builtin_amdgcn_mfma_f32_16x16x32_bf16(a2, bb0, acc[2][0], 0, 0, 0);
        acc[3][0] = __builtin_amdgcn_mfma_f32_16x16x32_bf16(a3, bb0, acc[3][0], 0, 0, 0);
        acc[0][1] = __builtin_amdgcn_mfma_f32_16x16x32_bf16(a0, bb1, acc[0][1], 0, 0, 0);
        acc[1][1] = __builtin_amdgcn_mfma_f32_16x16x32_bf16(a1, bb1, acc[1][1], 0, 0, 0);
        acc[2][1] = __builtin_amdgcn_mfma_f32_16x16x32_bf16(a2, bb1, acc[2][1], 0, 0, 0);
        acc[3][1] = __builtin_amdgcn_mfma_f32_16x16x32_bf16(a3, bb1, acc[3][1], 0, 0, 0);
    }
    __syncthreads();

    #pragma unroll
    for (int j = 0; j < 2; ++j) {
        int n = wave * 32 + j * 16 + col16;
        float bias = sb1[n];
        #pragma unroll
        for (int mt = 0; mt < 4; ++mt) {
            #pragma unroll
            for (int r = 0; r < 4; ++r) {
                int m = mt * 16 + quad * 4 + r;
                sH1[m * PAD1 + n] = (__bf16)fmaxf(acc[mt][j][r] + bias, 0.f);
            }
        }
    }
    __syncthreads();

    v4f acc2[4];
    #pragma unroll
    for (int mt = 0; mt < 4; ++mt) acc2[mt] = zero4;
    const __bf16* w2p = wt2 + (size_t)(wave * 16 + col16) * H1DIM;
    #pragma unroll
    for (int ks = 0; ks < 4; ++ks) {
        int k0 = ks * 32 + quad * 8;
        v8bf bb = *(const v8bf*)&w2p[k0];
        #pragma unroll
        for (int mt = 0; mt < 4; ++mt) {
            v8bf aa = *(const v8bf*)&sH1[(mt * 16 + col16) * PAD1 + k0];
            acc2[mt] = __builtin_amdgcn_mfma_f32_16x16x32_bf16(aa, bb, acc2[mt], 0, 0, 0);
        }
    }
    {
        int n = wave * 16 + col16;
        float bias = sb2[n];
        #pragma unroll
        for (int mt = 0; mt < 4; ++mt) {
            #pragma unroll
            for (int rr = 0; rr < 4; ++rr) {
                int m = mt * 16 + quad * 4 + rr;
                sH2[m * PAD2 + n] = (__bf16)fmaxf(acc2[mt][rr] + bias, 0.f);
            }
        }
    }
    __syncthreads();
    {
        int row = tid >> 2, q = tid & 3;
        float s = 0.f;
        #pragma unroll
        for (int kk = 0; kk < 16; ++kk) {
            int k = q * 16 + kk;
            s += (float)sH2[row * PAD2 + k] * sw3[k];
        }
        s += __shfl_xor(s, 1);
        s += __shfl_xor(s, 2);
        if (q == 0) {
            float x = s + sb3s;
            out[e0 + row] = fmaxf(x, 0.f) + log1pf(expf(-fabsf(x)));
        }
    }
}

extern "C" void kernel_launch(void* const* d_in, const int* in_sizes, int n_in,
                              void* d_out, int out_size, void* d_ws, size_t ws_size,
                              hipStream_t stream) {
    const float* z     = (const float*)d_in[0];
    const int*   eidx  = (const int*)d_in[1];
    const int*   btyp  = (const int*)d_in[2];
    const float* embed = (const float*)d_in[3];
    const float* W1    = (const float*)d_in[4];
    const float* b1    = (const float*)d_in[5];
    const float* W2    = (const float*)d_in[6];
    const float* b2    = (const float*)d_in[7];
    const float* W3    = (const float*)d_in[8];
    const float* b3    = (const float*)d_in[9];
    float* out = (float*)d_out;
    __bf16* ws = (__bf16*)d_ws;

    if (ws_size >= WS_SPLIT) {
        prep_split<<<167, 256, 0, stream>>>(W1, W2, embed, b1, ws);
        node_gemm<<<NGBLK, 256, 0, stream>>>(z, ws, ws);
        edge_kernel<<<EBLK, 256, 0, stream>>>(eidx, btyp, b2, W3, b3, ws, out);
    } else {
        prep_mono<<<(DIN * H1DIM + 255) / 256, 256, 0, stream>>>(W1, W2, ws);
        fused_mono<<<EBLK, 256, 0, stream>>>(z, eidx, btyp, embed,
                                             b1, b2, W3, b3, ws, out);
    }
}